// Round 2
// baseline (1312.052 us; speedup 1.0000x reference)
//
#include <hip/hip_runtime.h>

typedef _Float16 f16x8 __attribute__((ext_vector_type(8)));
typedef float f32x4 __attribute__((ext_vector_type(4)));

#define Dd  256
#define Hh  1024

// ---------------- prep: transpose + cast fp32 -> fp16 ----------------
// src: R x C fp32 (row-major), dst: C x R fp16 (row-major)
__global__ void transpose_cast_kernel(const float* __restrict__ src,
                                      _Float16* __restrict__ dst,
                                      int R, int C) {
    __shared__ float tile[32][33];
    const int bx = blockIdx.x * 32;
    const int by = blockIdx.y * 32;
    const int x = threadIdx.x;
    const int y0 = threadIdx.y;
#pragma unroll
    for (int i = 0; i < 4; ++i) {
        int y = y0 + i * 8;
        tile[y][x] = src[(by + y) * C + bx + x];
    }
    __syncthreads();
#pragma unroll
    for (int i = 0; i < 4; ++i) {
        int y = y0 + i * 8;
        dst[(bx + y) * R + by + x] = (_Float16)tile[x][y];
    }
}

// ---------------- main: weights LDS-resident, flag-based dataflow ----------------
// 256 blocks x 256 threads (4 waves), 1 block/CU. Block i: bt=i&15 (batch tile,
// 64 rows), s=i>>4. Phase 1: act[bt, s*64..+64] = tanh(z@W1slice+b1), W1 slice
// in LDS. Phase 2: k[bt, s*16..+16] = act@W2slice+b2, W2 slice in LDS; RK4 state
// z/zsum in registers. Cross-block handoff of act/z_arg via global + per-tile
// epoch flags (agent-scope release/acquire). Same-bt blocks are i ≡ bt (mod 16)
// -> same XCD under round-robin dispatch (L2/LLC locality heuristic only).
// Residency: 66 KB LDS -> 2 blocks/CU capacity >= 1/CU needed: no spin deadlock.
__global__ __launch_bounds__(256, 2) void ode_kernel(
    const float* __restrict__ z0, const float* __restrict__ tv,
    const float* __restrict__ b1, const float* __restrict__ b2,
    const _Float16* __restrict__ W1T,   // [Hh][Dd] fp16 (W1 transposed)
    const _Float16* __restrict__ W2T,   // [Dd][Hh] fp16 (W2 transposed)
    _Float16* __restrict__ z_arg,      // [1024][256] fp16
    _Float16* __restrict__ act,        // [1024][1024] fp16
    int* __restrict__ z_flag,          // [256] epochs, pre-zeroed
    int* __restrict__ act_flag,        // [256] epochs, pre-zeroed
    float* __restrict__ out) {
    __shared__ _Float16 W1s[64][Dd + 8];   // 33792 B, +8 pad: 2-way banks (free)
    __shared__ _Float16 W2s[16][Hh + 8];   // 33024 B

    const int tid  = threadIdx.x;
    const int w    = tid >> 6;
    const int lane = tid & 63;
    const int ln   = lane & 15;
    const int q    = lane >> 4;
    const int bt   = blockIdx.x & 15;
    const int s    = blockIdx.x >> 4;
    const int mrow = bt * 64 + w * 16;     // this wave's 16-row batch tile
    const int fi   = bt * 16 + s;          // this block's flag index

    // ---- stage weight slices into LDS (once) ----
    for (int c = tid; c < 64 * 32; c += 256) {
        int row = c >> 5, col = (c & 31) * 8;
        *(f16x8*)&W1s[row][col] = *(const f16x8*)&W1T[(s * 64 + row) * Dd + col];
    }
    for (int c = tid; c < 16 * 128; c += 256) {
        int row = c >> 7, col = (c & 127) * 8;
        *(f16x8*)&W2s[row][col] = *(const f16x8*)&W2T[(s * 16 + row) * Hh + col];
    }

    const float h = (tv[1] - tv[0]) * 0.125f;
    float bb1[4];
#pragma unroll
    for (int nt = 0; nt < 4; ++nt) bb1[nt] = b1[s * 64 + nt * 16 + ln];
    const float bb2 = b2[s * 16 + ln];

    // ---- init: load z0 chunk (phase-2 ownership), publish z_arg v1 ----
    f32x4 z, zsum;
#pragma unroll
    for (int r = 0; r < 4; ++r)
        z[r] = z0[(mrow + q * 4 + r) * Dd + s * 16 + ln];
#pragma unroll
    for (int r = 0; r < 4; ++r)
        z_arg[(mrow + q * 4 + r) * Dd + s * 16 + ln] = (_Float16)z[r];
    __syncthreads();   // drains all threads' stores (vmcnt) before release
    if (tid == 0)
        __hip_atomic_store(&z_flag[fi], 1, __ATOMIC_RELEASE, __HIP_MEMORY_SCOPE_AGENT);

#pragma unroll 1
    for (int ev = 0; ev < 32; ++ev) {
        const int ep = ev + 1;
        const int e  = ev & 3;

        // ---- phase 1: wait z_arg[bt] v=ep from 16 producers ----
        if (tid < 16)
            while (__hip_atomic_load(&z_flag[bt * 16 + tid], __ATOMIC_ACQUIRE,
                                     __HIP_MEMORY_SCOPE_AGENT) < ep) {}
        __syncthreads();
        __builtin_amdgcn_fence(__ATOMIC_ACQUIRE, "agent");

        f16x8 a1[8];
#pragma unroll
        for (int kk = 0; kk < 8; ++kk)
            a1[kk] = *(const f16x8*)&z_arg[(mrow + ln) * Dd + kk * 32 + q * 8];
#pragma unroll
        for (int nt = 0; nt < 4; ++nt) {
            f32x4 acc = {0.f, 0.f, 0.f, 0.f};
#pragma unroll
            for (int kk = 0; kk < 8; ++kk)
                acc = __builtin_amdgcn_mfma_f32_16x16x32_f16(
                        a1[kk], *(const f16x8*)&W1s[nt * 16 + ln][kk * 32 + q * 8],
                        acc, 0, 0, 0);
#pragma unroll
            for (int r = 0; r < 4; ++r) {
                float x = acc[r] + bb1[nt];
                float ex = __expf(2.0f * x);
                act[(mrow + q * 4 + r) * Hh + s * 64 + nt * 16 + ln] =
                    (_Float16)(1.0f - 2.0f / (ex + 1.0f));
            }
        }
        __syncthreads();   // all act stores drained
        if (tid == 0)
            __hip_atomic_store(&act_flag[fi], ep, __ATOMIC_RELEASE, __HIP_MEMORY_SCOPE_AGENT);

        // ---- phase 2: wait act[bt] v=ep from 16 producers ----
        if (tid < 16)
            while (__hip_atomic_load(&act_flag[bt * 16 + tid], __ATOMIC_ACQUIRE,
                                     __HIP_MEMORY_SCOPE_AGENT) < ep) {}
        __syncthreads();
        __builtin_amdgcn_fence(__ATOMIC_ACQUIRE, "agent");

        f32x4 acc2 = {0.f, 0.f, 0.f, 0.f};
#pragma unroll
        for (int kk = 0; kk < 32; ++kk) {
            f16x8 a2 = *(const f16x8*)&act[(mrow + ln) * Hh + kk * 32 + q * 8];
            acc2 = __builtin_amdgcn_mfma_f32_16x16x32_f16(
                     a2, *(const f16x8*)&W2s[ln][kk * 32 + q * 8], acc2, 0, 0, 0);
        }

        // ---- RK4 epilogue (registers) ----
        f32x4 kv, za;
#pragma unroll
        for (int r = 0; r < 4; ++r) kv[r] = acc2[r] + bb2;
        if (e == 0) {
            zsum = kv;
        } else if (e == 3) {
#pragma unroll
            for (int r = 0; r < 4; ++r) zsum[r] += kv[r];
        } else {
#pragma unroll
            for (int r = 0; r < 4; ++r) zsum[r] += 2.0f * kv[r];
        }
        if (e < 3) {
            const float c = (e == 2) ? h : 0.5f * h;
#pragma unroll
            for (int r = 0; r < 4; ++r) za[r] = z[r] + c * kv[r];
        } else {
#pragma unroll
            for (int r = 0; r < 4; ++r) { z[r] += (h * (1.0f / 6.0f)) * zsum[r]; za[r] = z[r]; }
        }
#pragma unroll
        for (int r = 0; r < 4; ++r)
            z_arg[(mrow + q * 4 + r) * Dd + s * 16 + ln] = (_Float16)za[r];
        __syncthreads();   // z_arg stores drained
        if (tid == 0)
            __hip_atomic_store(&z_flag[fi], ep + 1, __ATOMIC_RELEASE, __HIP_MEMORY_SCOPE_AGENT);
    }

    // ---- final state -> out (fp32) ----
#pragma unroll
    for (int r = 0; r < 4; ++r)
        out[(mrow + q * 4 + r) * Dd + s * 16 + ln] = z[r];
}

extern "C" void kernel_launch(void* const* d_in, const int* in_sizes, int n_in,
                              void* d_out, int out_size, void* d_ws, size_t ws_size,
                              hipStream_t stream) {
    const float* z0 = (const float*)d_in[0];
    const float* tv = (const float*)d_in[1];
    const float* W1 = (const float*)d_in[2];   // [256][1024]
    const float* b1 = (const float*)d_in[3];   // [1024]
    const float* W2 = (const float*)d_in[4];   // [1024][256]
    const float* b2 = (const float*)d_in[5];   // [256]
    float* out = (float*)d_out;

    uint8_t* ws = (uint8_t*)d_ws;
    int* z_flag   = (int*)ws;                       // 256 ints
    int* act_flag = z_flag + 256;                   // 256 ints (2 KB total)
    _Float16* W1T   = (_Float16*)(ws + 4096);       // [1024][256] 512 KB
    _Float16* W2T   = W1T + Hh * Dd;                // [256][1024] 512 KB
    _Float16* z_arg = W2T + Dd * Hh;                // [1024][256] 512 KB
    _Float16* act   = z_arg + 1024 * Dd;            // [1024][1024] 2 MB

    // flags must be zero every launch (ws is re-poisoned 0xAA by harness)
    hipMemsetAsync(ws, 0, 2048, stream);

    dim3 blk(32, 8);
    transpose_cast_kernel<<<dim3(Hh / 32, Dd / 32), blk, 0, stream>>>(W1, W1T, Dd, Hh);
    transpose_cast_kernel<<<dim3(Dd / 32, Hh / 32), blk, 0, stream>>>(W2, W2T, Hh, Dd);

    ode_kernel<<<256, 256, 0, stream>>>(z0, tv, b1, b2, W1T, W2T,
                                        z_arg, act, z_flag, act_flag, out);
}

// Round 3
// 969.142 us; speedup vs baseline: 1.3538x; 1.3538x over previous
//
#include <hip/hip_runtime.h>

typedef _Float16 f16x8 __attribute__((ext_vector_type(8)));
typedef float f32x4 __attribute__((ext_vector_type(4)));

#define Dd  256
#define Hh  1024
#define BM  16
#define ZSTR (Dd + 8)    // 264 fp16: breaks pow2 stride, 16B-aligned rows
#define ASTR (Hh + 8)    // 1032 fp16

// ---------------- prep: transpose + cast fp32 -> fp16 ----------------
__global__ void transpose_cast_kernel(const float* __restrict__ src,
                                      _Float16* __restrict__ dst,
                                      int R, int C) {
    __shared__ float tile[32][33];
    const int bx = blockIdx.x * 32;
    const int by = blockIdx.y * 32;
    const int x = threadIdx.x;
    const int y0 = threadIdx.y;
#pragma unroll
    for (int i = 0; i < 4; ++i) {
        int y = y0 + i * 8;
        tile[y][x] = src[(by + y) * C + bx + x];
    }
    __syncthreads();
#pragma unroll
    for (int i = 0; i < 4; ++i) {
        int y = y0 + i * 8;
        dst[(bx + y) * R + by + x] = (_Float16)tile[x][y];
    }
}

// ---------------- main: zero-sync, deep weight-load pipelining ----------------
// 64 blocks x 512 threads (8 waves), block owns 16 batch rows for the whole
// solve — no inter-block communication. Weights stream from L2/LLC each eval;
// round-1 post-mortem: only ~8 loads in flight -> 24 GB/s/CU latency-bound.
// Fix: rotating prefetch buffers keep ~32 weight fragments (32 KB/wave) in
// flight in both GEMMs. __launch_bounds__(512,2) -> 256 VGPR cap, 8 waves/CU.
__global__ __launch_bounds__(512, 2) void ode_kernel(
    const float* __restrict__ z0, const float* __restrict__ tv,
    const float* __restrict__ b1, const float* __restrict__ b2,
    const _Float16* __restrict__ W1T,   // [Hh][Dd] fp16 (W1 transposed)
    const _Float16* __restrict__ W2T,   // [Dd][Hh] fp16 (W2 transposed)
    float* __restrict__ out) {
    __shared__ _Float16 z_lds[BM][ZSTR];
    __shared__ _Float16 act_lds[BM][ASTR];

    const int tid  = threadIdx.x;
    const int w    = tid >> 6;
    const int lane = tid & 63;
    const int ln   = lane & 15;
    const int q    = lane >> 4;
    const int m0   = blockIdx.x * BM;

    const float h = (tv[1] - tv[0]) * 0.125f;

    float bb1[8];
#pragma unroll
    for (int nt = 0; nt < 8; ++nt) bb1[nt] = b1[w * 128 + nt * 16 + ln];
    float bb2v[2];
#pragma unroll
    for (int t = 0; t < 2; ++t) bb2v[t] = b2[w * 32 + t * 16 + ln];

    // per-wave weight base pointers (fragment origin for this lane)
    const _Float16* W1b = W1T + (w * 128 + ln) * Dd + q * 8;  // + nt*16*Dd + kk*32
    const _Float16* W2b = W2T + (w * 32 + ln) * Hh + q * 8;   // + t*16*Hh + kk*32

    // RK4 state in registers (MFMA C-layout): z[t][r] = z[m0+q*4+r][w*32+t*16+ln]
    f32x4 z[2], zsum[2];
#pragma unroll
    for (int t = 0; t < 2; ++t)
#pragma unroll
        for (int r = 0; r < 4; ++r)
            z[t][r] = z0[(m0 + q * 4 + r) * Dd + w * 32 + t * 16 + ln];
#pragma unroll
    for (int t = 0; t < 2; ++t)
#pragma unroll
        for (int r = 0; r < 4; ++r)
            z_lds[q * 4 + r][w * 32 + t * 16 + ln] = (_Float16)z[t][r];
    __syncthreads();

#pragma unroll 1
    for (int ev = 0; ev < 32; ++ev) {
        const int e = ev & 3;

        // ---- GEMM1: act[:, w*128..+128) = tanh(z_arg @ W1 + b1) ----
        f16x8 a1[8];
#pragma unroll
        for (int kk = 0; kk < 8; ++kk)
            a1[kk] = *(const f16x8*)&z_lds[ln][kk * 32 + q * 8];

        {
            // rotating depth-4 prefetch over nt: 32 fragments (32 KB/wave) in flight
            f16x8 bw[4][8];
#pragma unroll
            for (int p = 0; p < 4; ++p)
#pragma unroll
                for (int kk = 0; kk < 8; ++kk)
                    bw[p][kk] = *(const f16x8*)&W1b[(p * 16) * Dd + kk * 32];

#pragma unroll
            for (int nt = 0; nt < 8; ++nt) {
                const int cur = nt & 3;
                f32x4 acc = {0.f, 0.f, 0.f, 0.f};
#pragma unroll
                for (int kk = 0; kk < 8; ++kk)
                    acc = __builtin_amdgcn_mfma_f32_16x16x32_f16(a1[kk], bw[cur][kk], acc, 0, 0, 0);
                if (nt < 4) {   // refill consumed slot with nt+4's fragments
#pragma unroll
                    for (int kk = 0; kk < 8; ++kk)
                        bw[cur][kk] = *(const f16x8*)&W1b[((nt + 4) * 16) * Dd + kk * 32];
                }
#pragma unroll
                for (int r = 0; r < 4; ++r) {
                    float x = acc[r] + bb1[nt];
                    float ex = __expf(2.0f * x);
                    act_lds[q * 4 + r][w * 128 + nt * 16 + ln] =
                        (_Float16)(1.0f - 2.0f / (ex + 1.0f));
                }
            }
        }
        __syncthreads();

        // ---- GEMM2: k[:, w*32..+32) = act @ W2 + b2 ----
        f32x4 acc2[2] = {{0.f, 0.f, 0.f, 0.f}, {0.f, 0.f, 0.f, 0.f}};
        {
            // rotating depth-16 prefetch over kk: 32 fragments in flight
            f16x8 bw2[16][2];
#pragma unroll
            for (int p = 0; p < 16; ++p)
#pragma unroll
                for (int t = 0; t < 2; ++t)
                    bw2[p][t] = *(const f16x8*)&W2b[(t * 16) * Hh + p * 32];

#pragma unroll
            for (int kk = 0; kk < 32; ++kk) {
                const int cur = kk & 15;
                f16x8 a2 = *(const f16x8*)&act_lds[ln][kk * 32 + q * 8];
#pragma unroll
                for (int t = 0; t < 2; ++t)
                    acc2[t] = __builtin_amdgcn_mfma_f32_16x16x32_f16(a2, bw2[cur][t], acc2[t], 0, 0, 0);
                if (kk < 16) {
#pragma unroll
                    for (int t = 0; t < 2; ++t)
                        bw2[cur][t] = *(const f16x8*)&W2b[(t * 16) * Hh + (kk + 16) * 32];
                }
            }
        }

        // ---- RK4 epilogue (registers) ----
#pragma unroll
        for (int t = 0; t < 2; ++t) {
            f32x4 kv, za;
#pragma unroll
            for (int r = 0; r < 4; ++r) kv[r] = acc2[t][r] + bb2v[t];
            if (e == 0) {
                zsum[t] = kv;
            } else if (e == 3) {
#pragma unroll
                for (int r = 0; r < 4; ++r) zsum[t][r] += kv[r];
            } else {
#pragma unroll
                for (int r = 0; r < 4; ++r) zsum[t][r] += 2.0f * kv[r];
            }
            if (e < 3) {
                const float c = (e == 2) ? h : 0.5f * h;
#pragma unroll
                for (int r = 0; r < 4; ++r) za[r] = z[t][r] + c * kv[r];
            } else {
#pragma unroll
                for (int r = 0; r < 4; ++r) {
                    z[t][r] += (h * (1.0f / 6.0f)) * zsum[t][r];
                    za[r] = z[t][r];
                }
            }
#pragma unroll
            for (int r = 0; r < 4; ++r)
                z_lds[q * 4 + r][w * 32 + t * 16 + ln] = (_Float16)za[r];
        }
        __syncthreads();
    }

#pragma unroll
    for (int t = 0; t < 2; ++t)
#pragma unroll
        for (int r = 0; r < 4; ++r)
            out[(m0 + q * 4 + r) * Dd + w * 32 + t * 16 + ln] = z[t][r];
}

extern "C" void kernel_launch(void* const* d_in, const int* in_sizes, int n_in,
                              void* d_out, int out_size, void* d_ws, size_t ws_size,
                              hipStream_t stream) {
    const float* z0 = (const float*)d_in[0];
    const float* tv = (const float*)d_in[1];
    const float* W1 = (const float*)d_in[2];   // [256][1024]
    const float* b1 = (const float*)d_in[3];   // [1024]
    const float* W2 = (const float*)d_in[4];   // [1024][256]
    const float* b2 = (const float*)d_in[5];   // [256]
    float* out = (float*)d_out;

    _Float16* W1T = (_Float16*)d_ws;           // [1024][256] fp16, 512 KB
    _Float16* W2T = W1T + Hh * Dd;             // [256][1024] fp16, 512 KB

    dim3 blk(32, 8);
    transpose_cast_kernel<<<dim3(Hh / 32, Dd / 32), blk, 0, stream>>>(W1, W1T, Dd, Hh);
    transpose_cast_kernel<<<dim3(Dd / 32, Hh / 32), blk, 0, stream>>>(W2, W2T, Hh, Dd);

    ode_kernel<<<64, 512, 0, stream>>>(z0, tv, b1, b2, W1T, W2T, out);
}